// Round 5
// baseline (471.546 us; speedup 1.0000x reference)
//
#include <hip/hip_runtime.h>

typedef unsigned short u16;
typedef short bf16x8 __attribute__((ext_vector_type(8)));
typedef float f32x4 __attribute__((ext_vector_type(4)));
typedef unsigned short us8 __attribute__((ext_vector_type(8)));
typedef unsigned long long u64;

__device__ __forceinline__ u16 f2bf(float f) {
  unsigned u = __float_as_uint(f);
  u += 0x7fffu + ((u >> 16) & 1u);  // RNE (no NaNs in this workload)
  return (u16)(u >> 16);
}

// ---------------------------------------------------------------------------
// Workspace layout (bytes)
// ---------------------------------------------------------------------------
#define OFF_L6U 0u            // 64000x384 bf16 = 49,152,000
#define OFF_IDX1 49152000u    // 128x500 int
#define OFF_FPSD 49408000u    // fps dist state
#define OFF_FPSI 49670144u    // fps fidx state
#define OFF_WB   49671168u    // bf16 weight arena (N x Kp)

// ---------------------------------------------------------------------------
// FPS, butterfly formulation. key = (dist_bits<<32) | ~idx (exact fp32 order
// for dist>=0; ties -> smaller idx == np.argmax first-max; >=500 dup slots
// carry larger idx so they never win). Per-lane 8->1 cndmask tree carrying
// coords, then 6 butterfly mix steps (row_ror 1/2/4/8 via DPP + shfl_xor
// 16/32 via ds_bpermute) -> ALL lanes hold the winner (key,x,y,z): next
// centroid needs NO readlane / SGPR round trip. out[] stores are batched
// via a per-lane history register (one coalesced wave-store per 64 iters) —
// no per-iter exec-mask juggling.
// ---------------------------------------------------------------------------
template <int CTRL>
__device__ __forceinline__ unsigned dppu(unsigned v) {
  return (unsigned)__builtin_amdgcn_update_dpp(0, (int)v, CTRL, 0xF, 0xF, true);
}
template <int CTRL>
__device__ __forceinline__ float dppf(float v) {
  return __uint_as_float(dppu<CTRL>(__float_as_uint(v)));
}
__device__ __forceinline__ void ksel(u64& ak, float& ax, float& ay, float& az,
                                     u64 bk, float bx, float by, float bz) {
  bool g = bk > ak;
  ak = g ? bk : ak;
  ax = g ? bx : ax;
  ay = g ? by : ay;
  az = g ? bz : az;
}
template <int CTRL>
__device__ __forceinline__ void bstep_dpp(u64& k, float& x, float& y, float& z) {
  unsigned lo = (unsigned)k, hi = (unsigned)(k >> 32);
  unsigned olo = dppu<CTRL>(lo), ohi = dppu<CTRL>(hi);
  float ox = dppf<CTRL>(x), oy = dppf<CTRL>(y), oz = dppf<CTRL>(z);
  ksel(k, x, y, z, (((u64)ohi) << 32) | olo, ox, oy, oz);
}
__device__ __forceinline__ void bstep_shfl(int m, u64& k, float& x, float& y,
                                           float& z) {
  unsigned lo = (unsigned)k, hi = (unsigned)(k >> 32);
  unsigned olo = (unsigned)__shfl_xor((int)lo, m, 64);
  unsigned ohi = (unsigned)__shfl_xor((int)hi, m, 64);
  float ox = __shfl_xor(x, m, 64);
  float oy = __shfl_xor(y, m, 64);
  float oz = __shfl_xor(z, m, 64);
  ksel(k, x, y, z, (((u64)ohi) << 32) | olo, ox, oy, oz);
}

__device__ void fps_seg(const float4* cpt, int* out, const int* init1,
                        float* dstate, int* fstate, int b, int t0, int tcnt,
                        int lane) {
  __builtin_amdgcn_s_setprio(3);
  float px[8], py[8], pz[8], dist[8];
  unsigned nl[8];
  int base = lane * 8;
#pragma unroll
  for (int j = 0; j < 8; ++j) {
    int p = base + j;
    float4 c = cpt[p < 500 ? p : 0];
    px[j] = c.x; py[j] = c.y; pz[j] = c.z;
    nl[j] = ~(unsigned)p;
  }
  int fidx;
  if (t0 == 0) {
#pragma unroll
    for (int j = 0; j < 8; ++j) dist[j] = 1e10f;
    fidx = init1[b];
  } else {
#pragma unroll
    for (int j = 0; j < 8; ++j) dist[j] = dstate[(b * 64 + lane) * 8 + j];
    fidx = fstate[b];
  }
  float4 c0 = cpt[fidx];
  float cx = c0.x, cy = c0.y, cz = c0.z;

  int hist = 0;
  int tend = t0 + tcnt;  // t0 is a multiple of 64; tend <= 500
  for (int t = t0; t < tend; ++t) {
    // capture out[t] = fidx into lane (t&63)'s history reg (2 VALU, off-path)
    hist = (lane == (t & 63)) ? fidx : hist;
    if ((t & 63) == 63) out[(t & ~63) + lane] = hist;  // coalesced wave store
    if (t == 499) break;  // 499 emits but never updates
#pragma unroll
    for (int j = 0; j < 8; ++j) {
      float dx = __fsub_rn(px[j], cx);
      float dy = __fsub_rn(py[j], cy);
      float dz = __fsub_rn(pz[j], cz);
      float d = __fadd_rn(__fadd_rn(__fmul_rn(dx, dx), __fmul_rn(dy, dy)),
                          __fmul_rn(dz, dz));
      dist[j] = fminf(dist[j], d);
    }
    // per-lane 8 -> 4 (coords selected straight from px/py/pz)
    u64 k[4];
    float X[4], Y[4], Z[4];
#pragma unroll
    for (int j = 0; j < 4; ++j) {
      u64 ka = (((u64)__float_as_uint(dist[2 * j])) << 32) | nl[2 * j];
      u64 kb = (((u64)__float_as_uint(dist[2 * j + 1])) << 32) | nl[2 * j + 1];
      bool g = kb > ka;
      k[j] = g ? kb : ka;
      X[j] = g ? px[2 * j + 1] : px[2 * j];
      Y[j] = g ? py[2 * j + 1] : py[2 * j];
      Z[j] = g ? pz[2 * j + 1] : pz[2 * j];
    }
    ksel(k[0], X[0], Y[0], Z[0], k[1], X[1], Y[1], Z[1]);
    ksel(k[2], X[2], Y[2], Z[2], k[3], X[3], Y[3], Z[3]);
    ksel(k[0], X[0], Y[0], Z[0], k[2], X[2], Y[2], Z[2]);
    // butterfly: all 64 lanes converge to the global winner
    bstep_dpp<0x121>(k[0], X[0], Y[0], Z[0]);  // row_ror:1
    bstep_dpp<0x122>(k[0], X[0], Y[0], Z[0]);  // row_ror:2
    bstep_dpp<0x124>(k[0], X[0], Y[0], Z[0]);  // row_ror:4
    bstep_dpp<0x128>(k[0], X[0], Y[0], Z[0]);  // row_ror:8
    bstep_shfl(16, k[0], X[0], Y[0], Z[0]);
    bstep_shfl(32, k[0], X[0], Y[0], Z[0]);
    fidx = (int)(~(unsigned)k[0]);  // off critical path (feeds hist only)
    cx = X[0]; cy = Y[0]; cz = Z[0];  // already lane-uniform VGPRs
  }
  // tail flush for a partial last 64-group (e.g. iters 448..499)
  if ((tend & 63) != 0) {
    int fb = (tend - 1) & ~63;
    if (lane <= ((tend - 1) & 63)) out[fb + lane] = hist;
  }
  if (tend < 500) {
#pragma unroll
    for (int j = 0; j < 8; ++j) dstate[(b * 64 + lane) * 8 + j] = dist[j];
    if (lane == 0) fstate[b] = fidx;
  }
}

// ---------------------------------------------------------------------------
// Fused-MLP building blocks. 512 threads = 8 waves, grid 2(M) x 4(N).
// ---------------------------------------------------------------------------
template <int MI, int NI, int NP, int AG, int XC>
__device__ __forceinline__ void gemm_acc(
    f32x4 acc[MI][NI], const u16* __restrict__ aL, int Win, int smask,
    int arow0, const u16* const* aG, const u16* __restrict__ xc,
    const u16* __restrict__ bb, int Kp, int mrow, int quad) {
#pragma unroll
  for (int mi = 0; mi < MI; ++mi)
#pragma unroll
    for (int ni = 0; ni < NI; ++ni) acc[mi][ni] = f32x4{0.f, 0.f, 0.f, 0.f};
#pragma unroll
  for (int kp = 0; kp < NP + XC; ++kp) {
    bf16x8 af[MI];
#pragma unroll
    for (int mi = 0; mi < MI; ++mi) {
      int r = arow0 + mi * 16 + mrow;
      if (XC && kp == NP)
        af[mi] = *(const bf16x8*)(xc + r * 32 + ((quad ^ (r & 3)) << 3));
      else if (AG)
        af[mi] = *(const bf16x8*)(aG[mi] + kp * 32);
      else
        af[mi] = *(const bf16x8*)(aL + r * Win +
                                  (((kp * 4 + quad) ^ (r & smask)) << 3));
    }
    bf16x8 bf[NI];
#pragma unroll
    for (int ni = 0; ni < NI; ++ni)
      bf[ni] = *(const bf16x8*)(bb + (size_t)ni * 16 * Kp + kp * 32);
#pragma unroll
    for (int mi = 0; mi < MI; ++mi)
#pragma unroll
      for (int ni = 0; ni < NI; ++ni)
        acc[mi][ni] = __builtin_amdgcn_mfma_f32_16x16x32_bf16(
            af[mi], bf[ni], acc[mi][ni], 0, 0, 0);
  }
}

template <int MI, int NI>
__device__ __forceinline__ void ep_lds(const f32x4 acc[MI][NI], u16* out,
                                       int Wout, const float* __restrict__ bias,
                                       int n0, int arow0, int relu, int mrow,
                                       int quad) {
#pragma unroll
  for (int ni = 0; ni < NI; ++ni) {
    int col = n0 + ni * 16 + mrow;
    float bv = bias[col];
    int seg0 = col >> 3, lo = col & 7;
#pragma unroll
    for (int mi = 0; mi < MI; ++mi)
#pragma unroll
      for (int r = 0; r < 4; ++r) {
        int row = arow0 + mi * 16 + quad * 4 + r;
        float v = acc[mi][ni][r] + bv;
        if (relu) v = fmaxf(v, 0.f);
        out[row * Wout + ((seg0 ^ (row & 7)) << 3) + lo] = f2bf(v);
      }
  }
}

template <int MI, int NI>
__device__ __forceinline__ void ep_glb(const f32x4 acc[MI][NI],
                                       u16* __restrict__ out, int ldo,
                                       const float* __restrict__ bias, int n0,
                                       long grow0, long rowlim, int relu,
                                       int mrow, int quad) {
#pragma unroll
  for (int ni = 0; ni < NI; ++ni) {
    int col = n0 + ni * 16 + mrow;
    float bv = bias[col];
#pragma unroll
    for (int mi = 0; mi < MI; ++mi)
#pragma unroll
      for (int r = 0; r < 4; ++r) {
        long grow = grow0 + mi * 16 + quad * 4 + r;
        if (grow < rowlim) {
          float v = acc[mi][ni][r] + bv;
          if (relu) v = fmaxf(v, 0.f);
          out[(size_t)grow * ldo + col] = f2bf(v);
        }
      }
  }
}

// ---------------------------------------------------------------------------
// Fused stage A+B: 128 rows/block, chain feat->l1->l2->l3->(cat x)->l4->
// l5(LDS)->l6u(global). Dynamic LDS 104 KB -> 1 block/CU; FPS blocks
// (bid<128) own their CUs.
// ---------------------------------------------------------------------------
struct ABArgs {
  const u16 *w1, *w2, *pc1, *w3, *w4, *pc2;
  const float *b1, *b2, *pc1b, *b3, *b4, *pc2b;
};

#define AB_LDS_BYTES (98304 + 8192)

__global__ __launch_bounds__(512, 2) void fused_ab(
    ABArgs A, const float* __restrict__ x, const float* __restrict__ cW,
    const float* __restrict__ cb, u16* __restrict__ l6u,
    const int* __restrict__ init1, int* __restrict__ idx1,
    float* __restrict__ dstate, int* __restrict__ fstate, int t0, int tcnt) {
  extern __shared__ __align__(16) char smem[];
  u16* act = (u16*)smem;             // 128 x up-to-384
  u16* xcat = (u16*)(smem + 98304);  // 128 x 32
  int bid = blockIdx.x, t = threadIdx.x;
  if (bid < 128) {  // FPS continuation — dedicated CU
    float4* cpt = (float4*)smem;
    const float* xb = x + (size_t)bid * 1500;
    for (int p = t; p < 500; p += 512)
      cpt[p] = make_float4(xb[p * 3], xb[p * 3 + 1], xb[p * 3 + 2], 0.f);
    __syncthreads();
    if (t < 64)
      fps_seg(cpt, idx1 + bid * 500, init1, dstate, fstate, bid, t0, tcnt, t);
    return;
  }
  const int blk = bid - 128;
  const size_t rows0 = (size_t)blk * 128;
  // init: feat (conf,x,y,z) into act[W=32]; x into xcat[W=32]
  if (t < 128) {
    size_t gr = rows0 + t;
    float x0 = x[gr * 3], x1 = x[gr * 3 + 1], x2 = x[gr * 3 + 2];
    float z = x0 * cW[0] + x1 * cW[1] + x2 * cW[2] + cb[0];
    float conf = 1.0f / (1.0f + expf(-z));
    us8 fv;
    fv[0] = f2bf(conf); fv[1] = f2bf(x0); fv[2] = f2bf(x1); fv[3] = f2bf(x2);
    fv[4] = 0; fv[5] = 0; fv[6] = 0; fv[7] = 0;
    *(us8*)(act + t * 32 + ((t & 3) << 3)) = fv;
    us8 xv;
    xv[0] = fv[1]; xv[1] = fv[2]; xv[2] = fv[3];
    xv[3] = 0; xv[4] = 0; xv[5] = 0; xv[6] = 0; xv[7] = 0;
    *(us8*)(xcat + t * 32 + ((t & 3) << 3)) = xv;
  }
  if (t < 384) {  // zero pad segs 1..3 of both 32-wide buffers
    us8 zz = {0, 0, 0, 0, 0, 0, 0, 0};
    int r = t / 3, s = 1 + t % 3;
    *(us8*)(act + r * 32 + ((s ^ (r & 3)) << 3)) = zz;
    *(us8*)(xcat + r * 32 + ((s ^ (r & 3)) << 3)) = zz;
  }
  __syncthreads();
  const int w = t >> 6, lane = t & 63, mrow = lane & 15, quad = lane >> 4;
  const int wm = w >> 2, wn = w & 3;
  const int arow0 = wm * 64;
  {  // L1: feat(K=32) -> 64, relu
    f32x4 acc[4][1];
    const u16* bb = A.w1 + (size_t)(wn * 16 + mrow) * 32 + quad * 8;
    gemm_acc<4, 1, 1, 0, 0>(acc, act, 32, 3, arow0, nullptr, nullptr, bb, 32,
                            mrow, quad);
    __syncthreads();
    ep_lds<4, 1>(acc, act, 64, A.b1, wn * 16, arow0, 1, mrow, quad);
    __syncthreads();
  }
  {  // L2: 64 -> 256, relu
    f32x4 acc[4][4];
    const u16* bb = A.w2 + (size_t)(wn * 64 + mrow) * 64 + quad * 8;
    gemm_acc<4, 4, 2, 0, 0>(acc, act, 64, 7, arow0, nullptr, nullptr, bb, 64,
                            mrow, quad);
    __syncthreads();
    ep_lds<4, 4>(acc, act, 256, A.b2, wn * 64, arow0, 1, mrow, quad);
    __syncthreads();
  }
  {  // L3: pc1 256 -> 256, no relu
    f32x4 acc[4][4];
    const u16* bb = A.pc1 + (size_t)(wn * 64 + mrow) * 256 + quad * 8;
    gemm_acc<4, 4, 8, 0, 0>(acc, act, 256, 7, arow0, nullptr, nullptr, bb, 256,
                            mrow, quad);
    __syncthreads();
    ep_lds<4, 4>(acc, act, 256, A.pc1b, wn * 64, arow0, 0, mrow, quad);
    __syncthreads();
  }
  {  // L4: w3 [l3|x](K=256+32) -> 256, relu
    f32x4 acc[4][4];
    const u16* bb = A.w3 + (size_t)(wn * 64 + mrow) * 288 + quad * 8;
    gemm_acc<4, 4, 8, 0, 1>(acc, act, 256, 7, arow0, nullptr, xcat, bb, 288,
                            mrow, quad);
    __syncthreads();
    ep_lds<4, 4>(acc, act, 256, A.b3, wn * 64, arow0, 1, mrow, quad);
    __syncthreads();
  }
  {  // L5: w4 256 -> 384, relu, stays in LDS
    f32x4 acc[4][6];
    const u16* bb = A.w4 + (size_t)(wn * 96 + mrow) * 256 + quad * 8;
    gemm_acc<4, 6, 8, 0, 0>(acc, act, 256, 7, arow0, nullptr, nullptr, bb, 256,
                            mrow, quad);
    __syncthreads();
    ep_lds<4, 6>(acc, act, 384, A.b4, wn * 96, arow0, 1, mrow, quad);
    __syncthreads();
  }
  {  // L6: pc2 384 -> 384 (A from LDS), no relu -> l6u global
    f32x4 acc[4][6];
    const u16* bb = A.pc2 + (size_t)(wn * 96 + mrow) * 384 + quad * 8;
    gemm_acc<4, 6, 12, 0, 0>(acc, act, 384, 7, arow0, nullptr, nullptr, bb,
                             384, mrow, quad);
    ep_glb<4, 6>(acc, l6u, 384, A.pc2b, wn * 96, (long)(rows0 + arow0), 64000,
                 0, mrow, quad);
  }
}

// ---------------------------------------------------------------------------
// Fused stage C: 4 blocks/batch x 128 rows. Gathered A (l6u[idx1[p]]) via
// per-lane global ptrs; l7 stays in LDS; l8 -> per-batch col max -> atomicMax.
// Dynamic LDS: l7 96KB + xcat 8KB + red 2KB = 106KB -> 1 block/CU.
// ---------------------------------------------------------------------------
struct CArgs {
  const u16 *w5, *w6;
  const float *b5, *b6;
};

#define C_LDS_BYTES (98304 + 8192 + 2048)

__global__ __launch_bounds__(512, 2) void fused_c(
    CArgs C, const float* __restrict__ x, const u16* __restrict__ l6u,
    float* __restrict__ outf, const int* __restrict__ idx1) {
  extern __shared__ __align__(16) char smem[];
  u16* l7 = (u16*)smem;                       // 128 x 384
  u16* xcat = (u16*)(smem + 98304);           // 128 x 32
  float* red = (float*)(smem + 98304 + 8192); // 2 x 256
  int bid = blockIdx.x, t = threadIdx.x;
  const int b = bid >> 2, q = bid & 3;
  const int prow0 = q * 128;
  if (t < 128) {
    int p = prow0 + t, pe = p < 500 ? p : 0;
    const float* xp = x + ((size_t)b * 500 + pe) * 3;
    us8 xv;
    xv[0] = f2bf(xp[0]); xv[1] = f2bf(xp[1]); xv[2] = f2bf(xp[2]);
    xv[3] = 0; xv[4] = 0; xv[5] = 0; xv[6] = 0; xv[7] = 0;
    *(us8*)(xcat + t * 32 + ((t & 3) << 3)) = xv;
  }
  if (t < 384) {
    us8 zz = {0, 0, 0, 0, 0, 0, 0, 0};
    int r = t / 3, s = 1 + t % 3;
    *(us8*)(xcat + r * 32 + ((s ^ (r & 3)) << 3)) = zz;
  }
  __syncthreads();
  const int w = t >> 6, lane = t & 63, mrow = lane & 15, quad = lane >> 4;
  const int wm = w >> 2, wn = w & 3;
  const int arow0 = wm * 64;
  {  // L7: w5 [l6u_gathered|x](K=384+32) -> 384, relu -> l7 LDS
    const u16* aG[4];
#pragma unroll
    for (int mi = 0; mi < 4; ++mi) {
      int p = prow0 + arow0 + mi * 16 + mrow;
      int pe = p < 500 ? p : 0;
      int s = idx1[b * 500 + pe];
      aG[mi] = l6u + ((size_t)b * 500 + s) * 384 + quad * 8;
    }
    f32x4 acc[4][6];
    const u16* bb = C.w5 + (size_t)(wn * 96 + mrow) * 416 + quad * 8;
    gemm_acc<4, 6, 12, 1, 1>(acc, nullptr, 0, 0, arow0, aG, xcat, bb, 416,
                             mrow, quad);
    ep_lds<4, 6>(acc, l7, 384, C.b5, wn * 96, arow0, 1, mrow, quad);
  }
  __syncthreads();
  {  // L8: w6 384 -> 512 (A from l7 LDS), relu + per-batch col max
#pragma unroll
    for (int ph = 0; ph < 2; ++ph) {
      f32x4 acc[4][4];
      int n0 = ph * 256 + wn * 64;
      const u16* bb = C.w6 + (size_t)(n0 + mrow) * 384 + quad * 8;
      gemm_acc<4, 4, 12, 0, 0>(acc, l7, 384, 7, arow0, nullptr, nullptr, bb,
                               384, mrow, quad);
#pragma unroll
      for (int ni = 0; ni < 4; ++ni) {
        int cc = n0 + ni * 16 + mrow;
        float bv = C.b6[cc];
        float mx = 0.f;
#pragma unroll
        for (int mi = 0; mi < 4; ++mi)
#pragma unroll
          for (int r = 0; r < 4; ++r) {
            int p = prow0 + arow0 + mi * 16 + quad * 4 + r;
            float v = fmaxf(acc[mi][ni][r] + bv, 0.f);
            if (p < 500) mx = fmaxf(mx, v);
          }
        mx = fmaxf(mx, __shfl_xor(mx, 16, 64));
        mx = fmaxf(mx, __shfl_xor(mx, 32, 64));
        if (quad == 0) red[wm * 256 + wn * 64 + ni * 16 + mrow] = mx;
      }
      __syncthreads();
      if (t < 256) {
        float m = fmaxf(red[t], red[256 + t]);
        atomicMax((unsigned*)&outf[(size_t)b * 512 + ph * 256 + t],
                  __float_as_uint(m));
      }
      __syncthreads();
    }
  }
}

// ---------------------------------------------------------------------------
// prep: weight convert (N x Kp, k-pad zeros) + outf zero + FPS segment 0
// ---------------------------------------------------------------------------
struct PrepArgs {
  const float* wsrc[8];
  u16* wdst[8];
  int wN[8], wK[8], wKp[8];
  int wstart[9];
};

__global__ __launch_bounds__(256) void prep_kernel(
    PrepArgs pa, const float* __restrict__ x, float* __restrict__ outf,
    const int* __restrict__ init1, int* __restrict__ idx1,
    float* __restrict__ dstate, int* __restrict__ fstate, int tcnt) {
  __shared__ float4 cpt[512];
  int bid = blockIdx.x, t = threadIdx.x;
  if (bid < 128) {
    const float* xb = x + (size_t)bid * 1500;
    for (int p = t; p < 500; p += 256)
      cpt[p] = make_float4(xb[p * 3], xb[p * 3 + 1], xb[p * 3 + 2], 0.f);
    __syncthreads();
    if (t < 64)
      fps_seg(cpt, idx1 + bid * 500, init1, dstate, fstate, bid, 0, tcnt, t);
    return;
  }
  int i = (bid - 128) * 256 + t;
  int S = pa.wstart[8];
  if (i < S) {
    int wsel = 0;
#pragma unroll
    for (int j = 1; j < 8; ++j)
      if (i >= pa.wstart[j]) wsel = j;
    int local = i - pa.wstart[wsel];
    int Kp = pa.wKp[wsel];
    int n = local / Kp, k = local - n * Kp;
    pa.wdst[wsel][local] =
        (k < pa.wK[wsel]) ? f2bf(pa.wsrc[wsel][n * pa.wK[wsel] + k]) : (u16)0;
  } else if (i < S + 65536) {
    outf[i - S] = 0.f;
  }
}

// ---------------------------------------------------------------------------
extern "C" void kernel_launch(void* const* d_in, const int* in_sizes, int n_in,
                              void* d_out, int out_size, void* d_ws,
                              size_t ws_size, hipStream_t stream) {
  const float* x      = (const float*)d_in[0];
  const float* conf_W = (const float*)d_in[1];
  const float* conf_b = (const float*)d_in[2];
  const float* w1     = (const float*)d_in[3];
  const float* b1     = (const float*)d_in[4];
  const float* w2     = (const float*)d_in[5];
  const float* b2     = (const float*)d_in[6];
  const float* pc1_W  = (const float*)d_in[7];
  const float* pc1_b  = (const float*)d_in[8];
  const float* w3     = (const float*)d_in[9];
  const float* b3     = (const float*)d_in[10];
  const float* w4     = (const float*)d_in[11];
  const float* b4     = (const float*)d_in[12];
  const float* pc2_W  = (const float*)d_in[13];
  const float* pc2_b  = (const float*)d_in[14];
  const float* w5     = (const float*)d_in[15];
  const float* b5     = (const float*)d_in[16];
  const float* w6     = (const float*)d_in[17];
  const float* b6     = (const float*)d_in[18];
  const int* init1    = (const int*)d_in[20];

  char* ws = (char*)d_ws;
  u16* l6u = (u16*)(ws + OFF_L6U);
  int* idx1 = (int*)(ws + OFF_IDX1);
  float* dstate = (float*)(ws + OFF_FPSD);
  int* fstate = (int*)(ws + OFF_FPSI);
  u16* wb = (u16*)(ws + OFF_WB);
  float* outf = (float*)d_out;

  PrepArgs pa;
  const float* srcs[8] = {w1, w2, pc1_W, w3, w4, pc2_W, w5, w6};
  int Ns[8]  = {64, 256, 256, 256, 384, 384, 384, 512};
  int Ks[8]  = {4, 64, 256, 259, 256, 384, 387, 384};
  int Kps[8] = {32, 64, 256, 288, 256, 384, 416, 384};
  u16* WBp[8];
  int cum = 0;
  for (int i = 0; i < 8; ++i) {
    pa.wsrc[i] = srcs[i];
    pa.wdst[i] = WBp[i] = wb + cum;
    pa.wN[i] = Ns[i];
    pa.wK[i] = Ks[i];
    pa.wKp[i] = Kps[i];
    pa.wstart[i] = cum;
    cum += Ns[i] * Kps[i];
  }
  pa.wstart[8] = cum;
  int total = cum + 65536;

  // D1: weights + outf zero + FPS iters [0,64)
  prep_kernel<<<128 + (total + 255) / 256, 256, 0, stream>>>(
      pa, x, outf, init1, idx1, dstate, fstate, 64);

  // D2: fused A+B (500 MLP blocks, 128 rows each) + FPS iters [64,500)
  ABArgs A;
  A.w1 = WBp[0]; A.w2 = WBp[1]; A.pc1 = WBp[2];
  A.w3 = WBp[3]; A.w4 = WBp[4]; A.pc2 = WBp[5];
  A.b1 = b1; A.b2 = b2; A.pc1b = pc1_b; A.b3 = b3; A.b4 = b4; A.pc2b = pc2_b;
  fused_ab<<<128 + 500, 512, AB_LDS_BYTES, stream>>>(
      A, x, conf_W, conf_b, l6u, init1, idx1, dstate, fstate, 64, 436);

  // D3: fused C (gather + l7(LDS) + l8 + max), 128 rows/block
  CArgs Cg;
  Cg.w5 = WBp[6]; Cg.w6 = WBp[7]; Cg.b5 = b5; Cg.b6 = b6;
  fused_c<<<512, 512, C_LDS_BYTES, stream>>>(Cg, x, l6u, outf, idx1);
}

// Round 7
// 408.021 us; speedup vs baseline: 1.1557x; 1.1557x over previous
//
#include <hip/hip_runtime.h>

typedef unsigned short u16;
typedef short bf16x8 __attribute__((ext_vector_type(8)));
typedef float f32x4 __attribute__((ext_vector_type(4)));
typedef unsigned short us8 __attribute__((ext_vector_type(8)));
typedef unsigned short us4 __attribute__((ext_vector_type(4)));
typedef unsigned long long u64;

__device__ __forceinline__ u16 f2bf(float f) {
  unsigned u = __float_as_uint(f);
  u += 0x7fffu + ((u >> 16) & 1u);  // RNE (no NaNs in this workload)
  return (u16)(u >> 16);
}
__device__ __forceinline__ float rlf(float v, int l) {
  return __uint_as_float((unsigned)__builtin_amdgcn_readlane(__float_as_int(v), l));
}

// ---------------------------------------------------------------------------
// Workspace layout (bytes)
// ---------------------------------------------------------------------------
#define OFF_AP   0u           // Apart' f32: 64000x384x4 = 98,304,000
#define OFF_IDX1 98304000u    // 128x500 int
#define OFF_FPSD 98560000u    // fps dist state 128*64*8*4
#define OFF_FPSI 98822144u    // fps fidx state
#define OFF_WB   98824192u    // bf16 weight arena (N x Kp)

// ---------------------------------------------------------------------------
// FPS. Per iter: dist min-update; f32 max-reduce of dist ONLY (8->1 max3
// tree + 6 DPP fmax steps, 2 inst/step); readlane(63) -> SGPR max; winner =
// smallest idx with dist==max via 8 parallel cmp + min3 tree + ballot/ffs +
// 1 readlane; coords via ONE uniform LDS read cpt[fidx]. Exact fp32 order,
// np.argmax first-max tie-break (lane-major idx = lane*8+j; pad slots >=500
// mirror point 0 and lose ties to it by index order).
// ---------------------------------------------------------------------------
template <int CTRL>
__device__ __forceinline__ float dppmaxf(float v) {
  int s = __builtin_amdgcn_update_dpp(0, __float_as_int(v), CTRL, 0xF, 0xF, true);
  return fmaxf(v, __uint_as_float((unsigned)s));
}

__device__ void fps_seg(const float4* cpt, int* out, const int* init1,
                        float* dstate, int* fstate, int b, int t0, int tcnt,
                        int lane) {
  __builtin_amdgcn_s_setprio(3);  // prep: FPS waves co-run with convert blocks
  float px[8], py[8], pz[8], dist[8];
  int base = lane * 8;
#pragma unroll
  for (int j = 0; j < 8; ++j) {
    int p = base + j;
    float4 c = cpt[p < 500 ? p : 0];
    px[j] = c.x; py[j] = c.y; pz[j] = c.z;
  }
  int fidx;
  if (t0 == 0) {
#pragma unroll
    for (int j = 0; j < 8; ++j) dist[j] = 1e10f;
    fidx = init1[b];
  } else {
#pragma unroll
    for (int j = 0; j < 8; ++j) dist[j] = dstate[(b * 64 + lane) * 8 + j];
    fidx = fstate[b];
  }
  float4 c0 = cpt[fidx];
  float cx = c0.x, cy = c0.y, cz = c0.z;

  int hist = 0;
  int tend = t0 + tcnt;  // t0 multiple of 64
  for (int t = t0; t < tend; ++t) {
    hist = (lane == (t & 63)) ? fidx : hist;
    if ((t & 63) == 63) out[(t & ~63) + lane] = hist;  // coalesced wave store
    if (t == 499) break;
#pragma unroll
    for (int j = 0; j < 8; ++j) {
      float dx = __fsub_rn(px[j], cx);
      float dy = __fsub_rn(py[j], cy);
      float dz = __fsub_rn(pz[j], cz);
      float d = __fadd_rn(__fadd_rn(__fmul_rn(dx, dx), __fmul_rn(dy, dy)),
                          __fmul_rn(dz, dz));
      dist[j] = fminf(dist[j], d);
    }
    // max of 8 (v_max3 friendly)
    float t1 = fmaxf(fmaxf(dist[0], dist[1]), dist[2]);
    float t2 = fmaxf(fmaxf(dist[3], dist[4]), dist[5]);
    float t3 = fmaxf(fmaxf(dist[6], dist[7]), t1);
    float m = fmaxf(t2, t3);
    // wave max (dist only, 2 inst/step), winner value lands in lane 63
    m = dppmaxf<0x111>(m);
    m = dppmaxf<0x112>(m);
    m = dppmaxf<0x114>(m);
    m = dppmaxf<0x118>(m);
    m = dppmaxf<0x142>(m);
    m = dppmaxf<0x143>(m);
    float mf = rlf(m, 63);  // global max -> SGPR
    // smallest local slot with dist==mf (8 parallel cmp + min3 tree)
    int e0 = (dist[0] == mf) ? 0 : 8, e1 = (dist[1] == mf) ? 1 : 8;
    int e2 = (dist[2] == mf) ? 2 : 8, e3 = (dist[3] == mf) ? 3 : 8;
    int e4 = (dist[4] == mf) ? 4 : 8, e5 = (dist[5] == mf) ? 5 : 8;
    int e6 = (dist[6] == mf) ? 6 : 8, e7 = (dist[7] == mf) ? 7 : 8;
    int sA = min(min(e0, e1), e2);
    int sB = min(min(e3, e4), e5);
    int sC = min(min(e6, e7), sA);
    int sel = min(sB, sC);
    u64 mask = __ballot(sel != 8);
    int li = (int)__ffsll(mask) - 1;  // smallest lane = smallest idx range
    fidx = li * 8 + __builtin_amdgcn_readlane(sel, li);
    float4 cc = cpt[fidx];  // uniform LDS broadcast read
    cx = cc.x; cy = cc.y; cz = cc.z;
  }
  if ((tend & 63) != 0) {  // partial-group flush (e.g. 448..499)
    int fb = (tend - 1) & ~63;
    if (lane <= ((tend - 1) & 63)) out[fb + lane] = hist;
  }
  if (tend < 500) {
#pragma unroll
    for (int j = 0; j < 8; ++j) dstate[(b * 64 + lane) * 8 + j] = dist[j];
    if (lane == 0) fstate[b] = fidx;
  }
}

// ---------------------------------------------------------------------------
// Fused-MLP building blocks. 512 threads = 8 waves, grid 2(M) x 4(N).
// ---------------------------------------------------------------------------
template <int MI, int NI, int NP, int XC>
__device__ __forceinline__ void gemm_acc(
    f32x4 acc[MI][NI], const u16* __restrict__ aL, int Win, int smask,
    int arow0, const u16* __restrict__ xc, const u16* __restrict__ bb, int Kp,
    int mrow, int quad) {
#pragma unroll
  for (int mi = 0; mi < MI; ++mi)
#pragma unroll
    for (int ni = 0; ni < NI; ++ni) acc[mi][ni] = f32x4{0.f, 0.f, 0.f, 0.f};
#pragma unroll
  for (int kp = 0; kp < NP + XC; ++kp) {
    bf16x8 af[MI];
#pragma unroll
    for (int mi = 0; mi < MI; ++mi) {
      int r = arow0 + mi * 16 + mrow;
      if (XC && kp == NP)
        af[mi] = *(const bf16x8*)(xc + r * 32 + ((quad ^ (r & 3)) << 3));
      else
        af[mi] = *(const bf16x8*)(aL + r * Win +
                                  (((kp * 4 + quad) ^ (r & smask)) << 3));
    }
    bf16x8 bf[NI];
#pragma unroll
    for (int ni = 0; ni < NI; ++ni)
      bf[ni] = *(const bf16x8*)(bb + (size_t)ni * 16 * Kp + kp * 32);
#pragma unroll
    for (int mi = 0; mi < MI; ++mi)
#pragma unroll
      for (int ni = 0; ni < NI; ++ni)
        acc[mi][ni] = __builtin_amdgcn_mfma_f32_16x16x32_bf16(
            af[mi], bf[ni], acc[mi][ni], 0, 0, 0);
  }
}

template <int MI, int NI>
__device__ __forceinline__ void ep_lds(const f32x4 acc[MI][NI], u16* out,
                                       int Wout, const float* __restrict__ bias,
                                       int n0, int arow0, int relu, int mrow,
                                       int quad) {
#pragma unroll
  for (int ni = 0; ni < NI; ++ni) {
    int col = n0 + ni * 16 + mrow;
    float bv = bias[col];
    int seg0 = col >> 3, lo = col & 7;
#pragma unroll
    for (int mi = 0; mi < MI; ++mi)
#pragma unroll
      for (int r = 0; r < 4; ++r) {
        int row = arow0 + mi * 16 + quad * 4 + r;
        float v = acc[mi][ni][r] + bv;
        if (relu) v = fmaxf(v, 0.f);
        out[row * Wout + ((seg0 ^ (row & 7)) << 3) + lo] = f2bf(v);
      }
  }
}

// f32 global epilogue (Apart' = w5a@l6 + b5, no relu)
template <int MI, int NI>
__device__ __forceinline__ void ep_glbf(const f32x4 acc[MI][NI],
                                        float* __restrict__ out, int ldo,
                                        const float* __restrict__ bias, int n0,
                                        long grow0, long rowlim, int mrow,
                                        int quad) {
#pragma unroll
  for (int ni = 0; ni < NI; ++ni) {
    int col = n0 + ni * 16 + mrow;
    float bv = bias[col];
#pragma unroll
    for (int mi = 0; mi < MI; ++mi)
#pragma unroll
      for (int r = 0; r < 4; ++r) {
        long grow = grow0 + mi * 16 + quad * 4 + r;
        if (grow < rowlim)
          out[(size_t)grow * ldo + col] = acc[mi][ni][r] + bv;
      }
  }
}

// ---------------------------------------------------------------------------
// Fused stage A+B(+Apart): 128 rows/block, chain feat->l1->l2->l3->(cat x)->
// l4->l5(LDS)->l6(LDS)->Apart'(f32 global). FPS: 64 blocks x 2 batches
// (waves on separate SIMDs). Dynamic LDS 104KB -> 1 block/CU.
// ---------------------------------------------------------------------------
struct ABArgs {
  const u16 *w1, *w2, *pc1, *w3, *w4, *pc2, *w5;
  const float *b1, *b2, *pc1b, *b3, *b4, *pc2b, *b5;
};

#define AB_LDS_BYTES (98304 + 8192)

__global__ __launch_bounds__(512, 2) void fused_ab(
    ABArgs A, const float* __restrict__ x, const float* __restrict__ cW,
    const float* __restrict__ cb, float* __restrict__ apart,
    const int* __restrict__ init1, int* __restrict__ idx1,
    float* __restrict__ dstate, int* __restrict__ fstate, int t0, int tcnt) {
  extern __shared__ __align__(16) char smem[];
  u16* act = (u16*)smem;             // 128 x up-to-384
  u16* xcat = (u16*)(smem + 98304);  // 128 x 32
  int bid = blockIdx.x, t = threadIdx.x;
  if (bid < 64) {  // FPS: 2 batches per block, waves 0/1 on separate SIMDs
    float4* cpt = (float4*)smem;  // 1000 float4
    const float* xb = x + (size_t)bid * 3000;
    for (int p = t; p < 1000; p += 512)
      cpt[p] = make_float4(xb[p * 3], xb[p * 3 + 1], xb[p * 3 + 2], 0.f);
    __syncthreads();
    int wid = t >> 6;
    if (wid < 2) {
      int b = bid * 2 + wid;
      fps_seg(cpt + wid * 500, idx1 + b * 500, init1, dstate, fstate, b, t0,
              tcnt, t & 63);
    }
    return;
  }
  const int blk = bid - 64;
  const size_t rows0 = (size_t)blk * 128;
  // init: feat (conf,x,y,z) into act[W=32]; x into xcat[W=32]
  if (t < 128) {
    size_t gr = rows0 + t;
    float x0 = x[gr * 3], x1 = x[gr * 3 + 1], x2 = x[gr * 3 + 2];
    float z = x0 * cW[0] + x1 * cW[1] + x2 * cW[2] + cb[0];
    float conf = 1.0f / (1.0f + expf(-z));
    us8 fv;
    fv[0] = f2bf(conf); fv[1] = f2bf(x0); fv[2] = f2bf(x1); fv[3] = f2bf(x2);
    fv[4] = 0; fv[5] = 0; fv[6] = 0; fv[7] = 0;
    *(us8*)(act + t * 32 + ((t & 3) << 3)) = fv;
    us8 xv;
    xv[0] = fv[1]; xv[1] = fv[2]; xv[2] = fv[3];
    xv[3] = 0; xv[4] = 0; xv[5] = 0; xv[6] = 0; xv[7] = 0;
    *(us8*)(xcat + t * 32 + ((t & 3) << 3)) = xv;
  }
  if (t < 384) {  // zero pad segs 1..3 of both 32-wide buffers
    us8 zz = {0, 0, 0, 0, 0, 0, 0, 0};
    int r = t / 3, s = 1 + t % 3;
    *(us8*)(act + r * 32 + ((s ^ (r & 3)) << 3)) = zz;
    *(us8*)(xcat + r * 32 + ((s ^ (r & 3)) << 3)) = zz;
  }
  __syncthreads();
  const int w = t >> 6, lane = t & 63, mrow = lane & 15, quad = lane >> 4;
  const int wm = w >> 2, wn = w & 3;
  const int arow0 = wm * 64;
  {  // L1: feat(K=32) -> 64, relu
    f32x4 acc[4][1];
    const u16* bb = A.w1 + (size_t)(wn * 16 + mrow) * 32 + quad * 8;
    gemm_acc<4, 1, 1, 0>(acc, act, 32, 3, arow0, nullptr, bb, 32, mrow, quad);
    __syncthreads();
    ep_lds<4, 1>(acc, act, 64, A.b1, wn * 16, arow0, 1, mrow, quad);
    __syncthreads();
  }
  {  // L2: 64 -> 256, relu
    f32x4 acc[4][4];
    const u16* bb = A.w2 + (size_t)(wn * 64 + mrow) * 64 + quad * 8;
    gemm_acc<4, 4, 2, 0>(acc, act, 64, 7, arow0, nullptr, bb, 64, mrow, quad);
    __syncthreads();
    ep_lds<4, 4>(acc, act, 256, A.b2, wn * 64, arow0, 1, mrow, quad);
    __syncthreads();
  }
  {  // L3: pc1 256 -> 256, no relu
    f32x4 acc[4][4];
    const u16* bb = A.pc1 + (size_t)(wn * 64 + mrow) * 256 + quad * 8;
    gemm_acc<4, 4, 8, 0>(acc, act, 256, 7, arow0, nullptr, bb, 256, mrow, quad);
    __syncthreads();
    ep_lds<4, 4>(acc, act, 256, A.pc1b, wn * 64, arow0, 0, mrow, quad);
    __syncthreads();
  }
  {  // L4: w3 [l3|x](K=256+32) -> 256, relu
    f32x4 acc[4][4];
    const u16* bb = A.w3 + (size_t)(wn * 64 + mrow) * 288 + quad * 8;
    gemm_acc<4, 4, 8, 1>(acc, act, 256, 7, arow0, xcat, bb, 288, mrow, quad);
    __syncthreads();
    ep_lds<4, 4>(acc, act, 256, A.b3, wn * 64, arow0, 1, mrow, quad);
    __syncthreads();
  }
  {  // L5: w4 256 -> 384, relu, stays in LDS
    f32x4 acc[4][6];
    const u16* bb = A.w4 + (size_t)(wn * 96 + mrow) * 256 + quad * 8;
    gemm_acc<4, 6, 8, 0>(acc, act, 256, 7, arow0, nullptr, bb, 256, mrow, quad);
    __syncthreads();
    ep_lds<4, 6>(acc, act, 384, A.b4, wn * 96, arow0, 1, mrow, quad);
    __syncthreads();
  }
  {  // L6: pc2 384 -> 384, no relu, stays in LDS (bf16, as before)
    f32x4 acc[4][6];
    const u16* bb = A.pc2 + (size_t)(wn * 96 + mrow) * 384 + quad * 8;
    gemm_acc<4, 6, 12, 0>(acc, act, 384, 7, arow0, nullptr, bb, 384, mrow,
                          quad);
    __syncthreads();
    ep_lds<4, 6>(acc, act, 384, A.pc2b, wn * 96, arow0, 0, mrow, quad);
    __syncthreads();
  }
  {  // Apart' = w5a(384x384) @ l6 + b5 -> f32 global (FPS-independent!)
    f32x4 acc[4][6];
    const u16* bb = A.w5 + (size_t)(wn * 96 + mrow) * 416 + quad * 8;
    gemm_acc<4, 6, 12, 0>(acc, act, 384, 7, arow0, nullptr, bb, 416, mrow,
                          quad);
    ep_glbf<4, 6>(acc, apart, 384, A.b5, wn * 96, (long)(rows0 + arow0), 64000,
                  mrow, quad);
  }
}

// ---------------------------------------------------------------------------
// Fused stage C: 4 blocks/batch x 128 rows. Gather Apart'[b*500+idx1[p]]
// (f32) + w5b·x[p] -> relu -> bf16 l7 (LDS) -> l8 GEMM -> per-batch col max.
// Dynamic LDS: l7 96KB + w5b 6KB + red 2KB -> 1 block/CU.
// ---------------------------------------------------------------------------
#define C_LDS_BYTES (98304 + 6144 + 2048)

__global__ __launch_bounds__(512, 2) void fused_c(
    const u16* __restrict__ w6b, const float* __restrict__ b6,
    const float* __restrict__ x, const float* __restrict__ apart,
    const float* __restrict__ w5src, float* __restrict__ outf,
    const int* __restrict__ idx1) {
  extern __shared__ __align__(16) char smem[];
  u16* l7 = (u16*)smem;                        // 128 x 384, swizzled
  float* xw = (float*)(smem + 98304);          // [384][4]: w5b cols 0..2
  float* red = (float*)(smem + 98304 + 6144);  // 2 x 256
  int bid = blockIdx.x, t = threadIdx.x;
  const int b = bid >> 2, q = bid & 3;
  const int prow0 = q * 128;
  if (t < 384) {
    xw[t * 4 + 0] = w5src[(size_t)t * 387 + 384];
    xw[t * 4 + 1] = w5src[(size_t)t * 387 + 385];
    xw[t * 4 + 2] = w5src[(size_t)t * 387 + 386];
    xw[t * 4 + 3] = 0.f;
  }
  __syncthreads();
  {  // gather + Bpart + relu + bf16 -> l7 LDS (4 threads per row)
    int row = t >> 2;
    int p = prow0 + row, pe = p < 500 ? p : 0;
    int s = idx1[b * 500 + pe];
    const float* ap = apart + ((size_t)b * 500 + (size_t)s) * 384;  // FIX
    const float* xp = x + ((size_t)b * 500 + pe) * 3;
    float x0 = xp[0], x1 = xp[1], x2 = xp[2];
#pragma unroll
    for (int it = 0; it < 24; ++it) {
      int c = (t & 3) * 4 + it * 16;
      float4 a4 = *(const float4*)(ap + c);
      const float4* wv = (const float4*)(xw + c * 4);
      float v0 = fmaxf(a4.x + wv[0].x * x0 + wv[0].y * x1 + wv[0].z * x2, 0.f);
      float v1 = fmaxf(a4.y + wv[1].x * x0 + wv[1].y * x1 + wv[1].z * x2, 0.f);
      float v2 = fmaxf(a4.z + wv[2].x * x0 + wv[2].y * x1 + wv[2].z * x2, 0.f);
      float v3 = fmaxf(a4.w + wv[3].x * x0 + wv[3].y * x1 + wv[3].z * x2, 0.f);
      us4 pk;
      pk[0] = f2bf(v0); pk[1] = f2bf(v1); pk[2] = f2bf(v2); pk[3] = f2bf(v3);
      int seg = c >> 3, half = (c >> 2) & 1;
      *(us4*)(l7 + row * 384 + ((seg ^ (row & 7)) << 3) + half * 4) = pk;
    }
  }
  __syncthreads();
  const int w = t >> 6, lane = t & 63, mrow = lane & 15, quad = lane >> 4;
  const int wm = w >> 2, wn = w & 3;
  const int arow0 = wm * 64;
  {  // L8: w6 384 -> 512 (A from l7 LDS), relu + per-batch col max
#pragma unroll
    for (int ph = 0; ph < 2; ++ph) {
      f32x4 acc[4][4];
      int n0 = ph * 256 + wn * 64;
      const u16* bb = w6b + (size_t)(n0 + mrow) * 384 + quad * 8;
      gemm_acc<4, 4, 12, 0>(acc, l7, 384, 7, arow0, nullptr, bb, 384, mrow,
                            quad);
#pragma unroll
      for (int ni = 0; ni < 4; ++ni) {
        int cc = n0 + ni * 16 + mrow;
        float bv = b6[cc];
        float mx = 0.f;
#pragma unroll
        for (int mi = 0; mi < 4; ++mi)
#pragma unroll
          for (int r = 0; r < 4; ++r) {
            int p = prow0 + arow0 + mi * 16 + quad * 4 + r;
            float v = fmaxf(acc[mi][ni][r] + bv, 0.f);
            if (p < 500) mx = fmaxf(mx, v);
          }
        mx = fmaxf(mx, __shfl_xor(mx, 16, 64));
        mx = fmaxf(mx, __shfl_xor(mx, 32, 64));
        if (quad == 0) red[wm * 256 + wn * 64 + ni * 16 + mrow] = mx;
      }
      __syncthreads();
      if (t < 256) {
        float m = fmaxf(red[t], red[256 + t]);
        atomicMax((unsigned*)&outf[(size_t)b * 512 + ph * 256 + t],
                  __float_as_uint(m));
      }
      __syncthreads();
    }
  }
}

// ---------------------------------------------------------------------------
// prep: weight convert (N x Kp, k-pad zeros) + outf zero + FPS segment 0
// (64 blocks x 2 batches)
// ---------------------------------------------------------------------------
struct PrepArgs {
  const float* wsrc[8];
  u16* wdst[8];
  int wN[8], wK[8], wKp[8];
  int wstart[9];
};

__global__ __launch_bounds__(256) void prep_kernel(
    PrepArgs pa, const float* __restrict__ x, float* __restrict__ outf,
    const int* __restrict__ init1, int* __restrict__ idx1,
    float* __restrict__ dstate, int* __restrict__ fstate, int tcnt) {
  __shared__ float4 cpt[1000];
  int bid = blockIdx.x, t = threadIdx.x;
  if (bid < 64) {
    const float* xb = x + (size_t)bid * 3000;
    for (int p = t; p < 1000; p += 256)
      cpt[p] = make_float4(xb[p * 3], xb[p * 3 + 1], xb[p * 3 + 2], 0.f);
    __syncthreads();
    int wid = t >> 6;
    if (wid < 2) {
      int b = bid * 2 + wid;
      fps_seg(cpt + wid * 500, idx1 + b * 500, init1, dstate, fstate, b, 0,
              tcnt, t & 63);
    }
    return;
  }
  int i = (bid - 64) * 256 + t;
  int S = pa.wstart[8];
  if (i < S) {
    int wsel = 0;
#pragma unroll
    for (int j = 1; j < 8; ++j)
      if (i >= pa.wstart[j]) wsel = j;
    int local = i - pa.wstart[wsel];
    int Kp = pa.wKp[wsel];
    int n = local / Kp, k = local - n * Kp;
    pa.wdst[wsel][local] =
        (k < pa.wK[wsel]) ? f2bf(pa.wsrc[wsel][n * pa.wK[wsel] + k]) : (u16)0;
  } else if (i < S + 65536) {
    outf[i - S] = 0.f;
  }
}

// ---------------------------------------------------------------------------
extern "C" void kernel_launch(void* const* d_in, const int* in_sizes, int n_in,
                              void* d_out, int out_size, void* d_ws,
                              size_t ws_size, hipStream_t stream) {
  const float* x      = (const float*)d_in[0];
  const float* conf_W = (const float*)d_in[1];
  const float* conf_b = (const float*)d_in[2];
  const float* w1     = (const float*)d_in[3];
  const float* b1     = (const float*)d_in[4];
  const float* w2     = (const float*)d_in[5];
  const float* b2     = (const float*)d_in[6];
  const float* pc1_W  = (const float*)d_in[7];
  const float* pc1_b  = (const float*)d_in[8];
  const float* w3     = (const float*)d_in[9];
  const float* b3     = (const float*)d_in[10];
  const float* w4     = (const float*)d_in[11];
  const float* b4     = (const float*)d_in[12];
  const float* pc2_W  = (const float*)d_in[13];
  const float* pc2_b  = (const float*)d_in[14];
  const float* w5     = (const float*)d_in[15];
  const float* b5     = (const float*)d_in[16];
  const float* w6     = (const float*)d_in[17];
  const float* b6     = (const float*)d_in[18];
  const int* init1    = (const int*)d_in[20];

  char* ws = (char*)d_ws;
  float* apart = (float*)(ws + OFF_AP);
  int* idx1 = (int*)(ws + OFF_IDX1);
  float* dstate = (float*)(ws + OFF_FPSD);
  int* fstate = (int*)(ws + OFF_FPSI);
  u16* wb = (u16*)(ws + OFF_WB);
  float* outf = (float*)d_out;

  PrepArgs pa;
  const float* srcs[8] = {w1, w2, pc1_W, w3, w4, pc2_W, w5, w6};
  int Ns[8]  = {64, 256, 256, 256, 384, 384, 384, 512};
  int Ks[8]  = {4, 64, 256, 259, 256, 384, 387, 384};
  int Kps[8] = {32, 64, 256, 288, 256, 384, 416, 384};
  u16* WBp[8];
  int cum = 0;
  for (int i = 0; i < 8; ++i) {
    pa.wsrc[i] = srcs[i];
    pa.wdst[i] = WBp[i] = wb + cum;
    pa.wN[i] = Ns[i];
    pa.wK[i] = Ks[i];
    pa.wKp[i] = Kps[i];
    pa.wstart[i] = cum;
    cum += Ns[i] * Kps[i];
  }
  pa.wstart[8] = cum;
  int total = cum + 65536;

  // D1: weights + outf zero + FPS iters [0,64)
  prep_kernel<<<64 + (total + 255) / 256, 256, 0, stream>>>(
      pa, x, outf, init1, idx1, dstate, fstate, 64);

  // D2: fused A+B+Apart (500 MLP blocks) + FPS iters [64,500) in 64 blocks
  ABArgs A;
  A.w1 = WBp[0]; A.w2 = WBp[1]; A.pc1 = WBp[2];
  A.w3 = WBp[3]; A.w4 = WBp[4]; A.pc2 = WBp[5]; A.w5 = WBp[6];
  A.b1 = b1; A.b2 = b2; A.pc1b = pc1_b; A.b3 = b3; A.b4 = b4;
  A.pc2b = pc2_b; A.b5 = b5;
  fused_ab<<<64 + 500, 512, AB_LDS_BYTES, stream>>>(
      A, x, conf_W, conf_b, apart, init1, idx1, dstate, fstate, 64, 436);

  // D3: fused C (gather Apart' + Bpart + l8 + max), 128 rows/block
  fused_c<<<512, 512, C_LDS_BYTES, stream>>>(WBp[7], b6, x, apart, w5, outf,
                                             idx1);
}